// Round 1
// baseline (695.002 us; speedup 1.0000x reference)
//
#include <hip/hip_runtime.h>
#include <hip/hip_bf16.h>
#include <stdint.h>

typedef unsigned short u16;

#define B_   512
#define D_   512
#define C_   100000

#define SCALE_  64.0f
#define COSM_   0.8775825618903728f
#define SINM_   0.479425538604203f
#define TH_     (-0.8775825618903728f)
#define MM_     0.2397127693021015f
#define EPS_    1e-7f
#define SHIFT_  89.6f

#define AS1 __attribute__((address_space(1)))
#define AS3 __attribute__((address_space(3)))

typedef __attribute__((ext_vector_type(8))) short short8;
typedef __attribute__((ext_vector_type(4))) float floatx4;

__device__ inline float wave_reduce_sum(float v) {
    v += __shfl_xor(v, 1);
    v += __shfl_xor(v, 2);
    v += __shfl_xor(v, 4);
    v += __shfl_xor(v, 8);
    v += __shfl_xor(v, 16);
    v += __shfl_xor(v, 32);
    return v;
}

__device__ inline u16 f2bf(float x) {
    union { float f; uint32_t u; } v; v.f = x;
    uint32_t r = v.u + 0x7fffu + ((v.u >> 16) & 1u);  // RNE
    return (u16)(r >> 16);
}

// Normalize rows of an [nrows x 512] fp32 matrix; write bf16 copy (and
// optionally fp32 copy). One wave per row; 4 rows per 256-thread block.
__global__ __launch_bounds__(256) void norm_rows_kernel(
    const float* __restrict__ in, u16* __restrict__ out_bf16,
    float* __restrict__ out_f32) {
    int wv = threadIdx.x >> 6;
    int lane = threadIdx.x & 63;
    long row = (long)blockIdx.x * 4 + wv;
    const float4* rp = (const float4*)(in + row * D_);
    float4 f0 = rp[lane];
    float4 f1 = rp[lane + 64];
    float sq = f0.x*f0.x + f0.y*f0.y + f0.z*f0.z + f0.w*f0.w
             + f1.x*f1.x + f1.y*f1.y + f1.z*f1.z + f1.w*f1.w;
    sq = wave_reduce_sum(sq);
    float rn = 1.0f / sqrtf(sq);
    f0.x *= rn; f0.y *= rn; f0.z *= rn; f0.w *= rn;
    f1.x *= rn; f1.y *= rn; f1.z *= rn; f1.w *= rn;
    uint2 p0, p1;
    p0.x = (uint32_t)f2bf(f0.x) | ((uint32_t)f2bf(f0.y) << 16);
    p0.y = (uint32_t)f2bf(f0.z) | ((uint32_t)f2bf(f0.w) << 16);
    p1.x = (uint32_t)f2bf(f1.x) | ((uint32_t)f2bf(f1.y) << 16);
    p1.y = (uint32_t)f2bf(f1.z) | ((uint32_t)f2bf(f1.w) << 16);
    uint2* ob = (uint2*)(out_bf16 + row * D_);
    ob[lane] = p0;
    ob[lane + 64] = p1;
    if (out_f32) {
        float4* of = (float4*)(out_f32 + row * D_);
        of[lane] = f0;
        of[lane + 64] = f1;
    }
}

// Per-row b: pos = clip(dot(e_norm[b], w[gt]/||w[gt]||)), phi per ArcFace.
// Exact fp32 path (matches reference at the gt column).
__global__ __launch_bounds__(256) void phi_kernel(
    const float* __restrict__ e_f32, const float* __restrict__ w_raw,
    const int* __restrict__ gt, float* __restrict__ phi) {
    int wv = threadIdx.x >> 6;
    int lane = threadIdx.x & 63;
    int b = blockIdx.x * 4 + wv;
    int g = gt[b];
    const float4* ep = (const float4*)(e_f32 + (long)b * D_);
    const float4* wp = (const float4*)(w_raw + (long)g * D_);
    float4 e0 = ep[lane], e1 = ep[lane + 64];
    float4 w0 = wp[lane], w1 = wp[lane + 64];
    float dot = e0.x*w0.x + e0.y*w0.y + e0.z*w0.z + e0.w*w0.w
              + e1.x*w1.x + e1.y*w1.y + e1.z*w1.z + e1.w*w1.w;
    float sq  = w0.x*w0.x + w0.y*w0.y + w0.z*w0.z + w0.w*w0.w
              + w1.x*w1.x + w1.y*w1.y + w1.z*w1.z + w1.w*w1.w;
    dot = wave_reduce_sum(dot);
    sq  = wave_reduce_sum(sq);
    if (lane == 0) {
        float pos = dot / sqrtf(sq);
        pos = fminf(fmaxf(pos, -1.0f + EPS_), 1.0f - EPS_);
        float s2 = 1.0f - pos * pos;
        s2 = fminf(fmaxf(s2, EPS_), 1.0f - EPS_);
        float sin_t = sqrtf(s2);
        float ph = pos * COSM_ - sin_t * SINM_;
        ph = (pos > TH_) ? ph : (pos - MM_);
        phi[b] = ph;
    }
}

// Fused GEMM + ArcFace + exp-rowsum. 128x128 tile, BK=32, 16x16x32 bf16 MFMA,
// global_load_lds width-16 staging (m97 structure).
#define BM 128
#define BN 128
#define BK 32

__global__ __launch_bounds__(256) void gemm_arcface_kernel(
    const u16* __restrict__ a_g,   // e_bf16 [512][512]
    const u16* __restrict__ b_g,   // w_bf16 [100000][512]
    const float* __restrict__ phi, const int* __restrict__ gt,
    float* __restrict__ rowsum) {
    __shared__ u16 a_tile[BM * BK];
    __shared__ u16 b_tile[BN * BK];
    __shared__ float phi_s[BM];
    __shared__ int gt_s[BM];

    int tid = threadIdx.x;
    int m0 = blockIdx.y * BM;
    int c0 = blockIdx.x * BN;

    if (tid < BM) {
        phi_s[tid] = phi[m0 + tid];
        gt_s[tid] = gt[m0 + tid];
    }

    // staging geometry: thread t stages 16B at LDS byte offset t*16 per call
    int srow = tid >> 2;          // 0..63
    int scol = (tid & 3) * 8;     // element offset in k
    const u16* a_src0 = a_g + (long)(m0 + srow) * D_ + scol;
    const u16* a_src1 = a_g + (long)(m0 + 64 + srow) * D_ + scol;
    int brow0 = min(c0 + srow, C_ - 1);
    int brow1 = min(c0 + 64 + srow, C_ - 1);
    const u16* b_src0 = b_g + (long)brow0 * D_ + scol;
    const u16* b_src1 = b_g + (long)brow1 * D_ + scol;
    u16* a_dst0 = a_tile + srow * BK + scol;
    u16* a_dst1 = a_tile + (64 + srow) * BK + scol;
    u16* b_dst0 = b_tile + srow * BK + scol;
    u16* b_dst1 = b_tile + (64 + srow) * BK + scol;

    int wv = tid >> 6, lane = tid & 63;
    int low4 = lane & 15, quad = lane >> 4;
    int wm = (wv >> 1) * 64, wn = (wv & 1) * 64;

    floatx4 acc[4][4] = {};

    for (int kt = 0; kt < D_; kt += BK) {
        __syncthreads();
        __builtin_amdgcn_global_load_lds((const AS1 uint32_t*)(uintptr_t)(a_src0 + kt),
                                         (AS3 uint32_t*)(uintptr_t)a_dst0, 16, 0, 0);
        __builtin_amdgcn_global_load_lds((const AS1 uint32_t*)(uintptr_t)(a_src1 + kt),
                                         (AS3 uint32_t*)(uintptr_t)a_dst1, 16, 0, 0);
        __builtin_amdgcn_global_load_lds((const AS1 uint32_t*)(uintptr_t)(b_src0 + kt),
                                         (AS3 uint32_t*)(uintptr_t)b_dst0, 16, 0, 0);
        __builtin_amdgcn_global_load_lds((const AS1 uint32_t*)(uintptr_t)(b_src1 + kt),
                                         (AS3 uint32_t*)(uintptr_t)b_dst1, 16, 0, 0);
        __syncthreads();
        short8 af[4], bf[4];
#pragma unroll
        for (int i = 0; i < 4; i++) {
            af[i] = *(const short8*)(a_tile + (wm + i * 16 + low4) * BK + quad * 8);
            bf[i] = *(const short8*)(b_tile + (wn + i * 16 + low4) * BK + quad * 8);
        }
#pragma unroll
        for (int mi = 0; mi < 4; mi++)
#pragma unroll
            for (int ni = 0; ni < 4; ni++)
                acc[mi][ni] = __builtin_amdgcn_mfma_f32_16x16x32_bf16(
                    af[mi], bf[ni], acc[mi][ni], 0, 0, 0);
    }

    // Epilogue: per held value apply clip + hard-example reweight + gt-phi
    // substitution, exp with fixed shift, reduce per row, atomic into rowsum.
#pragma unroll
    for (int mi = 0; mi < 4; mi++) {
#pragma unroll
        for (int r = 0; r < 4; r++) {
            int rl = wm + mi * 16 + quad * 4 + r;  // row within block tile
            float ph = phi_s[rl];
            int g = gt_s[rl];
            float s = 0.0f;
#pragma unroll
            for (int ni = 0; ni < 4; ni++) {
                int c = c0 + wn + ni * 16 + low4;
                float v = acc[mi][ni][r];
                float cosv = fminf(fmaxf(v, -1.0f + EPS_), 1.0f - EPS_);
                float logit = (cosv > ph) ? (1.2f * cosv + 0.2f) : cosv;
                logit *= SCALE_;
                if (c == g) logit = SCALE_ * ph;
                if (c < C_) s += __expf(logit - SHIFT_);
            }
            s += __shfl_xor(s, 1);
            s += __shfl_xor(s, 2);
            s += __shfl_xor(s, 4);
            s += __shfl_xor(s, 8);
            if (low4 == 0) atomicAdd(&rowsum[m0 + rl], s);
        }
    }
}

__global__ __launch_bounds__(256) void loss_kernel(
    const float* __restrict__ rowsum, const float* __restrict__ phi,
    float* __restrict__ out) {
    __shared__ float red[4];
    int tid = threadIdx.x;
    float s = 0.0f;
    for (int b = tid; b < B_; b += 256)
        s += logf(rowsum[b]) + SHIFT_ - SCALE_ * phi[b];
    s = wave_reduce_sum(s);
    int wv = tid >> 6, lane = tid & 63;
    if (lane == 0) red[wv] = s;
    __syncthreads();
    if (tid == 0) out[0] = (red[0] + red[1] + red[2] + red[3]) * (1.0f / B_);
}

extern "C" void kernel_launch(void* const* d_in, const int* in_sizes, int n_in,
                              void* d_out, int out_size, void* d_ws, size_t ws_size,
                              hipStream_t stream) {
    const float* emb = (const float*)d_in[0];   // [512][512] f32
    const float* wgt = (const float*)d_in[1];   // [100000][512] f32
    const int* gt = (const int*)d_in[2];        // [512] int32
    float* out = (float*)d_out;

    char* ws = (char*)d_ws;
    u16* w_bf16 = (u16*)(ws);                       // 102,400,000 B
    u16* e_bf16 = (u16*)(ws + 102400000);           //     524,288 B
    float* e_f32 = (float*)(ws + 102924288);        //   1,048,576 B
    float* phi = (float*)(ws + 103972864);          //       2,048 B
    float* rowsum = (float*)(ws + 103974912);       //       2,048 B

    norm_rows_kernel<<<C_ / 4, 256, 0, stream>>>(wgt, w_bf16, nullptr);
    norm_rows_kernel<<<B_ / 4, 256, 0, stream>>>(emb, e_bf16, e_f32);
    phi_kernel<<<B_ / 4, 256, 0, stream>>>(e_f32, wgt, gt, phi);
    hipMemsetAsync(rowsum, 0, B_ * sizeof(float), stream);
    dim3 grid((C_ + BN - 1) / BN, B_ / BM);  // 782 x 4
    gemm_arcface_kernel<<<grid, 256, 0, stream>>>(e_bf16, w_bf16, phi, gt, rowsum);
    loss_kernel<<<1, 256, 0, stream>>>(rowsum, phi, out);
}

// Round 2
// 463.215 us; speedup vs baseline: 1.5004x; 1.5004x over previous
//
#include <hip/hip_runtime.h>
#include <hip/hip_bf16.h>
#include <stdint.h>

typedef unsigned short u16;
typedef __attribute__((ext_vector_type(8))) short short8;
typedef __attribute__((ext_vector_type(4))) float floatx4;

#define B_   512
#define D_   512
#define C_   100000

#define SCALE_  64.0f
#define COSM_   0.8775825618903728f
#define SINM_   0.479425538604203f
#define TH_     (-0.8775825618903728f)
#define MM_     0.2397127693021015f
#define EPS_    1e-7f
#define SHIFT_  89.6f

#define BN 64
#define BK 32

__device__ inline float wave_reduce_sum(float v) {
    v += __shfl_xor(v, 1);
    v += __shfl_xor(v, 2);
    v += __shfl_xor(v, 4);
    v += __shfl_xor(v, 8);
    v += __shfl_xor(v, 16);
    v += __shfl_xor(v, 32);
    return v;
}

__device__ inline u16 f2bf(float x) {
    union { float f; uint32_t u; } v; v.f = x;
    uint32_t r = v.u + 0x7fffu + ((v.u >> 16) & 1u);  // RNE
    return (u16)(r >> 16);
}

// Fused: normalize embedding rows -> e_bf16, and compute per-row phi from the
// exact fp32 path (e_norm . w[gt] / ||w[gt]||). One wave per row.
__global__ __launch_bounds__(256) void norm_e_phi_kernel(
    const float* __restrict__ emb, const float* __restrict__ w_raw,
    const int* __restrict__ gt, u16* __restrict__ e_bf16,
    float* __restrict__ phi) {
    int wv = threadIdx.x >> 6;
    int lane = threadIdx.x & 63;
    int b = blockIdx.x * 4 + wv;
    const float4* rp = (const float4*)(emb + (long)b * D_);
    float4 f0 = rp[lane], f1 = rp[lane + 64];
    float sq = f0.x*f0.x + f0.y*f0.y + f0.z*f0.z + f0.w*f0.w
             + f1.x*f1.x + f1.y*f1.y + f1.z*f1.z + f1.w*f1.w;
    sq = wave_reduce_sum(sq);
    float rn = 1.0f / sqrtf(sq);
    f0.x *= rn; f0.y *= rn; f0.z *= rn; f0.w *= rn;
    f1.x *= rn; f1.y *= rn; f1.z *= rn; f1.w *= rn;
    uint2 p0, p1;
    p0.x = (uint32_t)f2bf(f0.x) | ((uint32_t)f2bf(f0.y) << 16);
    p0.y = (uint32_t)f2bf(f0.z) | ((uint32_t)f2bf(f0.w) << 16);
    p1.x = (uint32_t)f2bf(f1.x) | ((uint32_t)f2bf(f1.y) << 16);
    p1.y = (uint32_t)f2bf(f1.z) | ((uint32_t)f2bf(f1.w) << 16);
    uint2* ob = (uint2*)(e_bf16 + (long)b * D_);
    ob[lane] = p0;
    ob[lane + 64] = p1;

    int g = gt[b];
    const float4* wp = (const float4*)(w_raw + (long)g * D_);
    float4 w0 = wp[lane], w1 = wp[lane + 64];
    float dt = f0.x*w0.x + f0.y*w0.y + f0.z*w0.z + f0.w*w0.w
             + f1.x*w1.x + f1.y*w1.y + f1.z*w1.z + f1.w*w1.w;
    float wsq = w0.x*w0.x + w0.y*w0.y + w0.z*w0.z + w0.w*w0.w
              + w1.x*w1.x + w1.y*w1.y + w1.z*w1.z + w1.w*w1.w;
    dt = wave_reduce_sum(dt);
    wsq = wave_reduce_sum(wsq);
    if (lane == 0) {
        float pos = dt / sqrtf(wsq);
        pos = fminf(fmaxf(pos, -1.0f + EPS_), 1.0f - EPS_);
        float s2 = 1.0f - pos * pos;
        s2 = fminf(fmaxf(s2, EPS_), 1.0f - EPS_);
        float sin_t = sqrtf(s2);
        float ph = pos * COSM_ - sin_t * SINM_;
        ph = (pos > TH_) ? ph : (pos - MM_);
        phi[b] = ph;
    }
}

// Single-pass GEMM over raw fp32 W with inline normalization + ArcFace + exp
// row-sums. BM=512 (full M -> B read exactly once), BN=64, BK=32.
// A fragments come straight from L2 (no LDS); B is fp32->bf16 converted in
// registers and double-buffered in LDS; per-row ||w||^2 accumulated on the fly.
// No global_load_lds => the per-iter barrier does NOT drain vmcnt, so next-iter
// A/B loads stay in flight across the barrier.
__global__ __launch_bounds__(256, 2) void gemm_arcface_fused(
    const u16* __restrict__ a_g,     // e_bf16 [512][512]
    const float* __restrict__ w_g,   // raw weight fp32 [100000][512]
    const float* __restrict__ phi, const int* __restrict__ gt,
    float* __restrict__ rowsum) {
    __shared__ __align__(16) u16 b_tile[2][BN * BK];  // 2 x 4 KB
    __shared__ float phi_s[B_];
    __shared__ int gt_s[B_];
    __shared__ float rnorm_s[BN];

    int tid = threadIdx.x;
    int c0 = blockIdx.x * BN;
    phi_s[tid] = phi[tid];
    phi_s[tid + 256] = phi[tid + 256];
    gt_s[tid] = gt[tid];
    gt_s[tid + 256] = gt[tid + 256];

    // B staging: thread t handles row rb = t>>2, LDS slot bslot = t&3, but
    // reads the XOR-swizzled global k-quad (breaks ds_read bank conflicts).
    int rb = tid >> 2;                       // 0..63
    int bslot = tid & 3;
    int bkq = bslot ^ ((tid >> 3) & 3);      // = bslot ^ ((rb>>1)&3)
    long brow_g = min(c0 + rb, C_ - 1);
    const float4* b_src = (const float4*)(w_g + brow_g * (long)D_ + bkq * 8);

    int wv = tid >> 6, lane = tid & 63;
    int low4 = lane & 15, quad = lane >> 4;
    int wm = wv * 128;                        // 4 waves cover M=512
    int lslot = quad ^ ((low4 >> 1) & 3);     // lane-uniform swizzled slot

    const u16* a_base = a_g + (long)(wm + low4) * D_ + quad * 8;
    int bf_off = low4 * BK + lslot * 8;       // + ni*16*BK per ni

    floatx4 acc[8][4] = {};
    float sq = 0.0f;

    // ---- prologue: kt = 0 ----
    float4 bv0 = b_src[0], bv1 = b_src[1];
    short8 afc[8];
#pragma unroll
    for (int mi = 0; mi < 8; mi++)
        afc[mi] = *(const short8*)(a_base + mi * 16 * D_);
    {
        union { u16 h[8]; uint4 q; } u;
        u.h[0] = f2bf(bv0.x); u.h[1] = f2bf(bv0.y);
        u.h[2] = f2bf(bv0.z); u.h[3] = f2bf(bv0.w);
        u.h[4] = f2bf(bv1.x); u.h[5] = f2bf(bv1.y);
        u.h[6] = f2bf(bv1.z); u.h[7] = f2bf(bv1.w);
        *(uint4*)&b_tile[0][rb * BK + bslot * 8] = u.q;
        sq += bv0.x*bv0.x + bv0.y*bv0.y + bv0.z*bv0.z + bv0.w*bv0.w
            + bv1.x*bv1.x + bv1.y*bv1.y + bv1.z*bv1.z + bv1.w*bv1.w;
    }
    __syncthreads();

#pragma unroll
    for (int kt = 0; kt < 16; kt++) {
        int p = kt & 1;
        short8 afn[8];
        float4 nv0, nv1;
        if (kt < 15) {
            nv0 = b_src[(kt + 1) * 8];
            nv1 = b_src[(kt + 1) * 8 + 1];
#pragma unroll
            for (int mi = 0; mi < 8; mi++)
                afn[mi] = *(const short8*)(a_base + mi * 16 * D_ + (kt + 1) * BK);
        }
        short8 bf[4];
#pragma unroll
        for (int ni = 0; ni < 4; ni++)
            bf[ni] = *(const short8*)(&b_tile[p][ni * 16 * BK + bf_off]);
#pragma unroll
        for (int mi = 0; mi < 8; mi++)
#pragma unroll
            for (int ni = 0; ni < 4; ni++)
                acc[mi][ni] = __builtin_amdgcn_mfma_f32_16x16x32_bf16(
                    afc[mi], bf[ni], acc[mi][ni], 0, 0, 0);
        if (kt < 15) {
            union { u16 h[8]; uint4 q; } u;
            u.h[0] = f2bf(nv0.x); u.h[1] = f2bf(nv0.y);
            u.h[2] = f2bf(nv0.z); u.h[3] = f2bf(nv0.w);
            u.h[4] = f2bf(nv1.x); u.h[5] = f2bf(nv1.y);
            u.h[6] = f2bf(nv1.z); u.h[7] = f2bf(nv1.w);
            *(uint4*)&b_tile[1 - p][rb * BK + bslot * 8] = u.q;
            sq += nv0.x*nv0.x + nv0.y*nv0.y + nv0.z*nv0.z + nv0.w*nv0.w
                + nv1.x*nv1.x + nv1.y*nv1.y + nv1.z*nv1.z + nv1.w*nv1.w;
#pragma unroll
            for (int mi = 0; mi < 8; mi++) afc[mi] = afn[mi];
        }
        __syncthreads();
    }

    // per-column 1/||w||: 4 staging threads per row hold disjoint k-slices
    sq += __shfl_xor(sq, 1);
    sq += __shfl_xor(sq, 2);
    if ((tid & 3) == 0) rnorm_s[rb] = 1.0f / sqrtf(sq);
    __syncthreads();

    // epilogue: normalize, clip, reweight, gt-substitute, exp, row-reduce
#pragma unroll
    for (int mi = 0; mi < 8; mi++) {
#pragma unroll
        for (int r = 0; r < 4; r++) {
            int row = wm + mi * 16 + quad * 4 + r;
            float ph = phi_s[row];
            int g = gt_s[row];
            float s = 0.0f;
#pragma unroll
            for (int ni = 0; ni < 4; ni++) {
                int cl = ni * 16 + low4;
                int c = c0 + cl;
                float v = acc[mi][ni][r] * rnorm_s[cl];
                v = fminf(fmaxf(v, -1.0f + EPS_), 1.0f - EPS_);
                float logit = (v > ph) ? (1.2f * v + 0.2f) : v;
                logit *= SCALE_;
                if (c == g) logit = SCALE_ * ph;
                s += (c < C_) ? __expf(logit - SHIFT_) : 0.0f;
            }
            s += __shfl_xor(s, 1);
            s += __shfl_xor(s, 2);
            s += __shfl_xor(s, 4);
            s += __shfl_xor(s, 8);
            if (low4 == 0) atomicAdd(&rowsum[row], s);
        }
    }
}

__global__ __launch_bounds__(256) void loss_kernel(
    const float* __restrict__ rowsum, const float* __restrict__ phi,
    float* __restrict__ out) {
    __shared__ float red[4];
    int tid = threadIdx.x;
    float s = 0.0f;
    for (int b = tid; b < B_; b += 256)
        s += logf(rowsum[b]) + SHIFT_ - SCALE_ * phi[b];
    s = wave_reduce_sum(s);
    int wv = tid >> 6, lane = tid & 63;
    if (lane == 0) red[wv] = s;
    __syncthreads();
    if (tid == 0) out[0] = (red[0] + red[1] + red[2] + red[3]) * (1.0f / B_);
}

extern "C" void kernel_launch(void* const* d_in, const int* in_sizes, int n_in,
                              void* d_out, int out_size, void* d_ws, size_t ws_size,
                              hipStream_t stream) {
    const float* emb = (const float*)d_in[0];   // [512][512] f32
    const float* wgt = (const float*)d_in[1];   // [100000][512] f32
    const int* gt = (const int*)d_in[2];        // [512] int32
    float* out = (float*)d_out;

    char* ws = (char*)d_ws;
    u16* e_bf16 = (u16*)(ws);                   //   524,288 B
    float* phi = (float*)(ws + 524288);         //     2,048 B
    float* rowsum = (float*)(ws + 526336);      //     2,048 B

    norm_e_phi_kernel<<<B_ / 4, 256, 0, stream>>>(emb, wgt, gt, e_bf16, phi);
    hipMemsetAsync(rowsum, 0, B_ * sizeof(float), stream);
    gemm_arcface_fused<<<(C_ + BN - 1) / BN, 256, 0, stream>>>(
        e_bf16, wgt, phi, gt, rowsum);
    loss_kernel<<<1, 256, 0, stream>>>(rowsum, phi, out);
}

// Round 3
// 449.082 us; speedup vs baseline: 1.5476x; 1.0315x over previous
//
#include <hip/hip_runtime.h>
#include <hip/hip_bf16.h>
#include <stdint.h>

typedef unsigned short u16;
typedef __attribute__((ext_vector_type(8))) short short8;
typedef __attribute__((ext_vector_type(4))) float floatx4;

#define B_   512
#define D_   512
#define C_   100000

#define SCALE_  64.0f
#define COSM_   0.8775825618903728f
#define SINM_   0.479425538604203f
#define TH_     (-0.8775825618903728f)
#define MM_     0.2397127693021015f
#define EPS_    1e-7f
#define SHIFT_  89.6f

#define BM 256
#define BN 64
#define BK 32

__device__ inline float wave_reduce_sum(float v) {
    v += __shfl_xor(v, 1);
    v += __shfl_xor(v, 2);
    v += __shfl_xor(v, 4);
    v += __shfl_xor(v, 8);
    v += __shfl_xor(v, 16);
    v += __shfl_xor(v, 32);
    return v;
}

__device__ inline u16 f2bf(float x) {
    union { float f; uint32_t u; } v; v.f = x;
    uint32_t r = v.u + 0x7fffu + ((v.u >> 16) & 1u);  // RNE
    return (u16)(r >> 16);
}

// Fused: normalize embedding rows -> e_bf16, per-row phi (exact fp32 path),
// and zero-init rowsum (replaces a separate memset dispatch).
__global__ __launch_bounds__(256) void norm_e_phi_kernel(
    const float* __restrict__ emb, const float* __restrict__ w_raw,
    const int* __restrict__ gt, u16* __restrict__ e_bf16,
    float* __restrict__ phi, float* __restrict__ rowsum) {
    if (threadIdx.x < 4) rowsum[blockIdx.x * 4 + threadIdx.x] = 0.0f;
    int wv = threadIdx.x >> 6;
    int lane = threadIdx.x & 63;
    int b = blockIdx.x * 4 + wv;
    const float4* rp = (const float4*)(emb + (long)b * D_);
    float4 f0 = rp[lane], f1 = rp[lane + 64];
    float sq = f0.x*f0.x + f0.y*f0.y + f0.z*f0.z + f0.w*f0.w
             + f1.x*f1.x + f1.y*f1.y + f1.z*f1.z + f1.w*f1.w;
    sq = wave_reduce_sum(sq);
    float rn = 1.0f / sqrtf(sq);
    f0.x *= rn; f0.y *= rn; f0.z *= rn; f0.w *= rn;
    f1.x *= rn; f1.y *= rn; f1.z *= rn; f1.w *= rn;
    uint2 p0, p1;
    p0.x = (uint32_t)f2bf(f0.x) | ((uint32_t)f2bf(f0.y) << 16);
    p0.y = (uint32_t)f2bf(f0.z) | ((uint32_t)f2bf(f0.w) << 16);
    p1.x = (uint32_t)f2bf(f1.x) | ((uint32_t)f2bf(f1.y) << 16);
    p1.y = (uint32_t)f2bf(f1.z) | ((uint32_t)f2bf(f1.w) << 16);
    uint2* ob = (uint2*)(e_bf16 + (long)b * D_);
    ob[lane] = p0;
    ob[lane + 64] = p1;

    int g = gt[b];
    const float4* wp = (const float4*)(w_raw + (long)g * D_);
    float4 w0 = wp[lane], w1 = wp[lane + 64];
    float dt = f0.x*w0.x + f0.y*w0.y + f0.z*w0.z + f0.w*w0.w
             + f1.x*w1.x + f1.y*w1.y + f1.z*w1.z + f1.w*w1.w;
    float wsq = w0.x*w0.x + w0.y*w0.y + w0.z*w0.z + w0.w*w0.w
              + w1.x*w1.x + w1.y*w1.y + w1.z*w1.z + w1.w*w1.w;
    dt = wave_reduce_sum(dt);
    wsq = wave_reduce_sum(wsq);
    if (lane == 0) {
        float pos = dt / sqrtf(wsq);
        pos = fminf(fmaxf(pos, -1.0f + EPS_), 1.0f - EPS_);
        float s2 = 1.0f - pos * pos;
        s2 = fminf(fmaxf(s2, EPS_), 1.0f - EPS_);
        float sin_t = sqrtf(s2);
        float ph = pos * COSM_ - sin_t * SINM_;
        ph = (pos > TH_) ? ph : (pos - MM_);
        phi[b] = ph;
    }
}

__device__ inline void cvt_store(const float4& v0, const float4& v1,
                                 u16* dst, float& sq) {
    union { u16 h[8]; uint4 q; } u;
    u.h[0] = f2bf(v0.x); u.h[1] = f2bf(v0.y);
    u.h[2] = f2bf(v0.z); u.h[3] = f2bf(v0.w);
    u.h[4] = f2bf(v1.x); u.h[5] = f2bf(v1.y);
    u.h[6] = f2bf(v1.z); u.h[7] = f2bf(v1.w);
    *(uint4*)dst = u.q;
    sq += v0.x*v0.x + v0.y*v0.y + v0.z*v0.z + v0.w*v0.w
        + v1.x*v1.x + v1.y*v1.y + v1.z*v1.z + v1.w*v1.w;
}

// GEMM over raw fp32 W with inline normalization + ArcFace + exp row-sums.
// BM=256 (M split in 2 -> acc=64 regs/thread, no spill), BN=64, BK=32.
// Grid interleaves the two M-halves of each c-tile (bx = c*2 + mh) so the
// second half hits L2/L3 on W. B double-buffered in LDS with depth-2
// register prefetch; A fragments straight from L1/L2. One barrier per K-step.
__global__ __launch_bounds__(256, 3) void gemm_arcface_fused(
    const u16* __restrict__ a_g,     // e_bf16 [512][512]
    const float* __restrict__ w_g,   // raw weight fp32 [100000][512]
    const float* __restrict__ phi, const int* __restrict__ gt,
    float* __restrict__ rowsum) {
    __shared__ __align__(16) u16 b_tile[2][BN * BK];  // 2 x 4 KB
    __shared__ float phi_s[BM];
    __shared__ int gt_s[BM];
    __shared__ float rnorm_s[BN];

    int tid = threadIdx.x;
    int c0 = (blockIdx.x >> 1) * BN;
    int m0 = (blockIdx.x & 1) * BM;

    phi_s[tid] = phi[m0 + tid];
    gt_s[tid] = gt[m0 + tid];

    // B staging: thread t -> row rb=t>>2, LDS k-slot bslot=t&3, XOR-swizzled
    // global k-quad (bank-conflict-free, verified 0 conflicts in R2).
    int rb = tid >> 2;
    int bslot = tid & 3;
    int bkq = bslot ^ ((rb >> 1) & 3);
    long brow_g = min(c0 + rb, C_ - 1);
    const float4* b_src = (const float4*)(w_g + brow_g * (long)D_ + bkq * 8);
    u16* b_dst0 = &b_tile[0][rb * BK + bslot * 8];
    u16* b_dst1 = &b_tile[1][rb * BK + bslot * 8];

    int wv = tid >> 6, lane = tid & 63;
    int low4 = lane & 15, quad = lane >> 4;
    int lslot = quad ^ ((low4 >> 1) & 3);
    const u16* a_base = a_g + (long)(m0 + wv * 64 + low4) * D_ + quad * 8;
    int bf_off = low4 * BK + lslot * 8;

    floatx4 acc[4][4] = {};
    float sq = 0.0f;
    float4 bv[2][2];     // 2-deep B register pipeline
    short8 afc[4];

    // prologue: kt=0 B -> tile0; kt=1 B in flight
    bv[0][0] = b_src[0]; bv[0][1] = b_src[1];
    cvt_store(bv[0][0], bv[0][1], b_dst0, sq);
    bv[1][0] = b_src[8]; bv[1][1] = b_src[9];
    __syncthreads();

#pragma unroll
    for (int kt = 0; kt < 16; kt++) {
        int p = kt & 1;
        // issue B(kt+2) into the slot freed when B(kt) was converted
        if (kt < 14) {
            bv[p][0] = b_src[(kt + 2) * 8];
            bv[p][1] = b_src[(kt + 2) * 8 + 1];
        }
        // A fragments for this k-tile (L1/L2-warm; compiler hoists under cap)
#pragma unroll
        for (int mi = 0; mi < 4; mi++)
            afc[mi] = *(const short8*)(a_base + (long)mi * 16 * D_ + kt * BK);
        short8 bf[4];
#pragma unroll
        for (int ni = 0; ni < 4; ni++)
            bf[ni] = *(const short8*)(&b_tile[p][ni * 16 * BK + bf_off]);
#pragma unroll
        for (int mi = 0; mi < 4; mi++)
#pragma unroll
            for (int ni = 0; ni < 4; ni++)
                acc[mi][ni] = __builtin_amdgcn_mfma_f32_16x16x32_bf16(
                    afc[mi], bf[ni], acc[mi][ni], 0, 0, 0);
        // convert B(kt+1) into the other LDS buffer
        if (kt < 15)
            cvt_store(bv[1 - p][0], bv[1 - p][1], p ? b_dst0 : b_dst1, sq);
        __syncthreads();
    }

    // per-column 1/||w||: the 4 staging threads of a row hold disjoint slices
    sq += __shfl_xor(sq, 1);
    sq += __shfl_xor(sq, 2);
    if ((tid & 3) == 0) rnorm_s[rb] = 1.0f / sqrtf(sq);
    __syncthreads();

    // epilogue: normalize, clip, reweight, gt-substitute, exp, row-reduce
#pragma unroll
    for (int mi = 0; mi < 4; mi++) {
#pragma unroll
        for (int r = 0; r < 4; r++) {
            int rl = wv * 64 + mi * 16 + quad * 4 + r;
            float ph = phi_s[rl];
            int g = gt_s[rl];
            float s = 0.0f;
#pragma unroll
            for (int ni = 0; ni < 4; ni++) {
                int cl = ni * 16 + low4;
                int c = c0 + cl;
                float v = acc[mi][ni][r] * rnorm_s[cl];
                v = fminf(fmaxf(v, -1.0f + EPS_), 1.0f - EPS_);
                float logit = (v > ph) ? (1.2f * v + 0.2f) : v;
                logit *= SCALE_;
                if (c == g) logit = SCALE_ * ph;
                s += (c < C_) ? __expf(logit - SHIFT_) : 0.0f;
            }
            s += __shfl_xor(s, 1);
            s += __shfl_xor(s, 2);
            s += __shfl_xor(s, 4);
            s += __shfl_xor(s, 8);
            if (low4 == 0) atomicAdd(&rowsum[m0 + rl], s);
        }
    }
}

__global__ __launch_bounds__(256) void loss_kernel(
    const float* __restrict__ rowsum, const float* __restrict__ phi,
    float* __restrict__ out) {
    __shared__ float red[4];
    int tid = threadIdx.x;
    float s = 0.0f;
    for (int b = tid; b < B_; b += 256)
        s += logf(rowsum[b]) + SHIFT_ - SCALE_ * phi[b];
    s = wave_reduce_sum(s);
    int wv = tid >> 6, lane = tid & 63;
    if (lane == 0) red[wv] = s;
    __syncthreads();
    if (tid == 0) out[0] = (red[0] + red[1] + red[2] + red[3]) * (1.0f / B_);
}

extern "C" void kernel_launch(void* const* d_in, const int* in_sizes, int n_in,
                              void* d_out, int out_size, void* d_ws, size_t ws_size,
                              hipStream_t stream) {
    const float* emb = (const float*)d_in[0];   // [512][512] f32
    const float* wgt = (const float*)d_in[1];   // [100000][512] f32
    const int* gt = (const int*)d_in[2];        // [512] int32
    float* out = (float*)d_out;

    char* ws = (char*)d_ws;
    u16* e_bf16 = (u16*)(ws);                   //   524,288 B
    float* phi = (float*)(ws + 524288);         //     2,048 B
    float* rowsum = (float*)(ws + 526336);      //     2,048 B

    norm_e_phi_kernel<<<B_ / 4, 256, 0, stream>>>(emb, wgt, gt, e_bf16, phi, rowsum);
    int nc = (C_ + BN - 1) / BN;                // 1563 c-tiles
    gemm_arcface_fused<<<nc * 2, 256, 0, stream>>>(e_bf16, wgt, phi, gt, rowsum);
    loss_kernel<<<1, 256, 0, stream>>>(rowsum, phi, out);
}